// Round 1
// baseline (108.270 us; speedup 1.0000x reference)
//
#include <hip/hip_runtime.h>

#define BB 4
#define NN 128
#define LK 16384      // n*n
#define DD 64
#define HH 4
#define DHH 16
#define TI 8          // q-rows per block
#define NI (NN/TI)    // 16
#define TL 1024       // l-chunk per block
#define NL (LK/TL)    // 16
#define NTHREADS 256
#define JITER (TL/NTHREADS) // 4

// ---- mask dtype detection: 0=int32, 1=uint8, 2=float32 ----
__global__ void detect_mode(const void* __restrict__ qmask, int* __restrict__ flag){
  if (threadIdx.x == 0){
    const unsigned int* w = (const unsigned int*)qmask;
    int v_u8 = 0, v_i32 = 0, v_f32 = 0;
    for (int t = 0; t < 128; ++t){   // 512 bytes, valid under every interpretation
      unsigned int x = w[t];
      if (x == 0u) continue;
      if (x == 1u){ v_i32++; continue; }
      if (x == 0x3f800000u){ v_f32++; continue; }
      v_u8++;  // multi-byte 0/1 patterns (or anything else) => byte-mask
    }
    int mode = 0;
    if (v_u8 > v_i32 && v_u8 > v_f32) mode = 1;
    else if (v_f32 > v_i32) mode = 2;
    *flag = mode;
  }
}

__device__ __forceinline__ bool mget(const void* __restrict__ p, int idx, int mode){
  if (mode == 1) return ((const unsigned char*)p)[idx] != 0;
  if (mode == 2) return ((const float*)p)[idx] != 0.0f;
  return ((const int*)p)[idx] != 0;
}

__device__ __forceinline__ float dot16(float4 q0, float4 q1, float4 q2, float4 q3,
                                       float4 k0, float4 k1, float4 k2, float4 k3){
  float d;
  d = q0.x*k0.x;        d = fmaf(q0.y,k0.y,d); d = fmaf(q0.z,k0.z,d); d = fmaf(q0.w,k0.w,d);
  d = fmaf(q1.x,k1.x,d); d = fmaf(q1.y,k1.y,d); d = fmaf(q1.z,k1.z,d); d = fmaf(q1.w,k1.w,d);
  d = fmaf(q2.x,k2.x,d); d = fmaf(q2.y,k2.y,d); d = fmaf(q2.z,k2.z,d); d = fmaf(q2.w,k2.w,d);
  d = fmaf(q3.x,k3.x,d); d = fmaf(q3.y,k3.y,d); d = fmaf(q3.z,k3.z,d); d = fmaf(q3.w,k3.w,d);
  return d;
}

// ---- pass 1: per-row sum of exp(logit) over this block's l-chunk ----
__global__ __launch_bounds__(NTHREADS) void k1_rowsum(
    const float* __restrict__ qA, const float* __restrict__ kA,
    const void* __restrict__ qm, const void* __restrict__ km,
    const int* __restrict__ flag, float* __restrict__ partials)
{
  const int mode = *flag;
  const int lc = blockIdx.x;
  const int it = blockIdx.y;
  const int b  = blockIdx.z >> 2;
  const int h  = blockIdx.z & 3;
  const int t  = threadIdx.x;

  float s[TI];
  #pragma unroll
  for (int i = 0; i < TI; ++i) s[i] = 0.0f;

  for (int j = 0; j < JITER; ++j){
    const int l  = lc*TL + j*NTHREADS + t;
    const int jn = l >> 7, kn = l & 127;
    const bool kv = (jn != kn) && mget(km, b*LK + l, mode);
    const float4* kp = (const float4*)(kA + ((size_t)(b*LK + l))*DD + h*DHH);
    const float4 k0 = kp[0], k1 = kp[1], k2 = kp[2], k3 = kp[3];
    #pragma unroll
    for (int i = 0; i < TI; ++i){
      const int ig = it*TI + i;
      const float4* qp = (const float4*)(qA + ((size_t)(b*NN + ig))*DD + h*DHH);
      const float d = dot16(qp[0], qp[1], qp[2], qp[3], k0, k1, k2, k3);
      const bool valid = kv && (ig != jn) && (ig != kn) && mget(qm, b*NN + ig, mode);
      s[i] += valid ? __expf(d * 0.25f) : 0.0f;
    }
  }

  // 64-lane butterfly reduce per row
  #pragma unroll
  for (int i = 0; i < TI; ++i){
    float v = s[i];
    #pragma unroll
    for (int off = 32; off > 0; off >>= 1) v += __shfl_xor(v, off);
    s[i] = v;
  }
  __shared__ float red[NTHREADS/64][TI];
  const int wave = t >> 6, lane = t & 63;
  if (lane == 0){
    #pragma unroll
    for (int i = 0; i < TI; ++i) red[wave][i] = s[i];
  }
  __syncthreads();
  if (t < TI){
    float v = 0.0f;
    #pragma unroll
    for (int w = 0; w < NTHREADS/64; ++w) v += red[w][t];
    partials[(((b*NI + it)*NL) + lc)*(HH*TI) + h*TI + t] = v;
  }
}

// ---- pass 1b: reduce l-chunk partials -> reciprocal row sums ----
__global__ void k1_finalize(const float* __restrict__ partials, float* __restrict__ R){
  const int row = blockIdx.x*blockDim.x + threadIdx.x;   // row = (b*128+i)*4+h
  if (row >= BB*NN*HH) return;
  const int h = row & 3;
  const int i = (row >> 2) & 127;
  const int b = row >> 9;
  const int it = i / TI, il = i % TI;
  float ssum = 0.0f;
  for (int lc = 0; lc < NL; ++lc)
    ssum += partials[(((b*NI + it)*NL) + lc)*(HH*TI) + h*TI + il];
  R[row] = ssum > 0.0f ? 1.0f/ssum : 0.0f;
}

// ---- pass 2: recompute logits, write normalized alpha ----
__global__ __launch_bounds__(NTHREADS) void k2_emit(
    const float* __restrict__ qA, const float* __restrict__ kA,
    const void* __restrict__ qm, const void* __restrict__ km,
    const int* __restrict__ flag, const float* __restrict__ R,
    float* __restrict__ out)
{
  const int mode = *flag;
  const int lc = blockIdx.x;
  const int it = blockIdx.y;
  const int b  = blockIdx.z >> 2;
  const int h  = blockIdx.z & 3;
  const int t  = threadIdx.x;

  for (int j = 0; j < JITER; ++j){
    const int l  = lc*TL + j*NTHREADS + t;
    const int jn = l >> 7, kn = l & 127;
    const bool kv = (jn != kn) && mget(km, b*LK + l, mode);
    const float4* kp = (const float4*)(kA + ((size_t)(b*LK + l))*DD + h*DHH);
    const float4 k0 = kp[0], k1 = kp[1], k2 = kp[2], k3 = kp[3];
    #pragma unroll
    for (int i = 0; i < TI; ++i){
      const int ig = it*TI + i;
      const float4* qp = (const float4*)(qA + ((size_t)(b*NN + ig))*DD + h*DHH);
      const float d = dot16(qp[0], qp[1], qp[2], qp[3], k0, k1, k2, k3);
      const bool valid = kv && (ig != jn) && (ig != kn) && mget(qm, b*NN + ig, mode);
      const float r = R[(b*NN + ig)*HH + h];
      out[(size_t)((h*BB + b)*NN + ig)*LK + l] = valid ? __expf(d * 0.25f) * r : 0.0f;
    }
  }
}

extern "C" void kernel_launch(void* const* d_in, const int* in_sizes, int n_in,
                              void* d_out, int out_size, void* d_ws, size_t ws_size,
                              hipStream_t stream)
{
  const float* qA = (const float*)d_in[0];
  const float* kA = (const float*)d_in[1];
  const void*  qm = d_in[2];
  const void*  km = d_in[3];
  float* out = (float*)d_out;

  int*   flag     = (int*)d_ws;
  float* partials = (float*)((char*)d_ws + 256);
  const size_t partials_bytes = (size_t)BB*NI*NL*HH*TI*sizeof(float); // 128 KB
  float* R        = (float*)((char*)d_ws + 256 + partials_bytes);

  detect_mode<<<1, 64, 0, stream>>>(qm, flag);
  dim3 grid(NL, NI, BB*HH);
  k1_rowsum<<<grid, NTHREADS, 0, stream>>>(qA, kA, qm, km, flag, partials);
  k1_finalize<<<(BB*NN*HH + 255)/256, 256, 0, stream>>>(partials, R);
  k2_emit<<<grid, NTHREADS, 0, stream>>>(qA, kA, qm, km, flag, R, out);
}